// Round 1
// baseline (2328.872 us; speedup 1.0000x reference)
//
#include <hip/hip_runtime.h>

// ---------------- small elementwise kernels ----------------

__global__ void k_fill1(float* p, int n) {
    int i = blockIdx.x * blockDim.x + threadIdx.x;
    if (i < n) p[i] = 1.0f;
}

__global__ void k_deg(const int* __restrict__ col, const float* __restrict__ w,
                      float* __restrict__ deg, int E) {
    int i = blockIdx.x * blockDim.x + threadIdx.x;
    if (i < E) atomicAdd(&deg[col[i]], w[i]);
}

__global__ void k_dinv(float* deg, int n) {
    int i = blockIdx.x * blockDim.x + threadIdx.x;
    if (i < n) {
        float d = deg[i];
        deg[i] = d > 0.0f ? rsqrtf(d) : 0.0f;
    }
}

__global__ void k_norm(const int* __restrict__ row, const int* __restrict__ col,
                       const float* __restrict__ w, const float* __restrict__ dinv,
                       float* __restrict__ norm, int E) {
    int i = blockIdx.x * blockDim.x + threadIdx.x;
    if (i < E) norm[i] = dinv[row[i]] * w[i] * dinv[col[i]];
}

// ---------------- fp32 tiled GEMM: C[M,Nc] = A[M,K] @ B[K,Nc] ----------------
// block = 256 threads (16x16), tile 64x64, each thread 4x4, BK=16.
// FUSE: additionally write out2[i,j] = dinv[i]^2 * acc + bias[j] (self-loop + bias
// for layer 2, plain store since it runs before the edge scatter on d_out).

#define BM 64
#define BN 64
#define BK 16

template <bool FUSE>
__global__ void k_gemm(const float* __restrict__ A, const float* __restrict__ B,
                       float* __restrict__ C, int M, int Nc, int K,
                       const float* __restrict__ dinv, const float* __restrict__ bias,
                       float* __restrict__ out2) {
    __shared__ float As[BK][BM + 1];
    __shared__ float Bs[BK][BN];

    const int t  = threadIdx.x;
    const int tx = t & 15;        // 0..15 -> N dir (x4)
    const int ty = t >> 4;        // 0..15 -> M dir (x4)
    const int bm = blockIdx.y * BM;
    const int bn = blockIdx.x * BN;

    float acc[4][4] = {};

    for (int k0 = 0; k0 < K; k0 += BK) {
        #pragma unroll
        for (int l = 0; l < 4; ++l) {
            int idx = t + l * 256;        // 0..1023
            int i  = idx >> 4;            // row in tile 0..63
            int kk = idx & 15;
            As[kk][i] = (bm + i < M) ? A[(size_t)(bm + i) * K + k0 + kk] : 0.0f;
        }
        #pragma unroll
        for (int l = 0; l < 4; ++l) {
            int idx = t + l * 256;
            int kk = idx >> 6;            // 0..15
            int j  = idx & 63;
            Bs[kk][j] = B[(size_t)(k0 + kk) * Nc + bn + j];
        }
        __syncthreads();
        #pragma unroll
        for (int kk = 0; kk < BK; ++kk) {
            float a[4], b[4];
            #pragma unroll
            for (int u = 0; u < 4; ++u) a[u] = As[kk][ty * 4 + u];
            #pragma unroll
            for (int v = 0; v < 4; ++v) b[v] = Bs[kk][tx * 4 + v];
            #pragma unroll
            for (int u = 0; u < 4; ++u)
                #pragma unroll
                for (int v = 0; v < 4; ++v) acc[u][v] += a[u] * b[v];
        }
        __syncthreads();
    }

    #pragma unroll
    for (int u = 0; u < 4; ++u) {
        int i = bm + ty * 4 + u;
        if (i < M) {
            float di2 = 0.0f;
            if (FUSE) { float di = dinv[i]; di2 = di * di; }
            #pragma unroll
            for (int v = 0; v < 4; ++v) {
                int j = bn + tx * 4 + v;
                size_t o = (size_t)i * Nc + j;
                C[o] = acc[u][v];
                if (FUSE) out2[o] = di2 * acc[u][v] + bias[j];
            }
        }
    }
}

// ---------------- edge aggregation (scatter with atomics) ----------------
// F=256: one feature per thread, 16 edges per block.
__global__ void k_agg256(const int* __restrict__ row, const int* __restrict__ col,
                         const float* __restrict__ norm, const float* __restrict__ h,
                         float* __restrict__ out, int E) {
    int f = threadIdx.x;
    int e0 = blockIdx.x * 16;
    int e1 = min(e0 + 16, E);
    for (int e = e0; e < e1; ++e) {
        int r = row[e], c = col[e];
        float nv = norm[e];
        atomicAdd(&out[(size_t)c * 256 + f], nv * h[(size_t)r * 256 + f]);
    }
}

// F=128: 2 edges in flight per 256-thread block, 16 edges per block.
__global__ void k_agg128(const int* __restrict__ row, const int* __restrict__ col,
                         const float* __restrict__ norm, const float* __restrict__ h,
                         float* __restrict__ out, int E) {
    int f   = threadIdx.x & 127;
    int sub = threadIdx.x >> 7;
    int base = blockIdx.x * 16;
    #pragma unroll
    for (int k = 0; k < 8; ++k) {
        int e = base + k * 2 + sub;
        if (e < E) {
            int r = row[e], c = col[e];
            float nv = norm[e];
            atomicAdd(&out[(size_t)c * 128 + f], nv * h[(size_t)r * 128 + f]);
        }
    }
}

// ---------------- finalize layer 1: += self-loop + bias, ReLU, in place -------
template <int F>
__global__ void k_final_relu(float* __restrict__ agg, const float* __restrict__ h,
                             const float* __restrict__ dinv, const float* __restrict__ bias,
                             int total) {
    int idx = blockIdx.x * blockDim.x + threadIdx.x;
    if (idx < total) {
        int i = idx / F;
        int f = idx & (F - 1);
        float di = dinv[i];
        float v = agg[idx] + di * di * h[idx] + bias[f];
        agg[idx] = v > 0.0f ? v : 0.0f;
    }
}

// ---------------- launcher ----------------

extern "C" void kernel_launch(void* const* d_in, const int* in_sizes, int n_in,
                              void* d_out, int out_size, void* d_ws, size_t ws_size,
                              hipStream_t stream) {
    const float* x  = (const float*)d_in[0];
    const int*   ei = (const int*)d_in[1];   // int32 on device (JAX x64 disabled)
    const float* ew = (const float*)d_in[2];
    const float* W1 = (const float*)d_in[3];
    const float* b1 = (const float*)d_in[4];
    const float* W2 = (const float*)d_in[5];
    const float* b2 = (const float*)d_in[6];
    float* out = (float*)d_out;

    const int E    = in_sizes[2];
    const int H    = in_sizes[4];       // 256
    const int Fout = in_sizes[6];       // 128
    const int Fin  = in_sizes[3] / H;   // 256
    const int N    = in_sizes[0] / Fin; // 50000

    const int* row = ei;
    const int* col = ei + E;

    float* ws   = (float*)d_ws;
    float* dinv = ws;                         // N
    float* norm = dinv + N;                   // E
    float* h1   = norm + E;                   // N*H
    float* agg1 = h1 + (size_t)N * H;         // N*H (becomes relu'd layer-1 output)
    float* h2   = agg1 + (size_t)N * H;       // N*Fout

    hipMemsetAsync(agg1, 0, (size_t)N * H * sizeof(float), stream);

    // normalization
    k_fill1<<<(N + 255) / 256, 256, 0, stream>>>(dinv, N);       // deg starts at 1 (self loop)
    k_deg<<<(E + 255) / 256, 256, 0, stream>>>(col, ew, dinv, E);
    k_dinv<<<(N + 255) / 256, 256, 0, stream>>>(dinv, N);
    k_norm<<<(E + 255) / 256, 256, 0, stream>>>(row, col, ew, dinv, norm, E);

    // layer 1: h1 = x @ W1
    k_gemm<false><<<dim3(H / BN, (N + BM - 1) / BM), 256, 0, stream>>>(
        x, W1, h1, N, H, Fin, nullptr, nullptr, nullptr);
    // edge scatter into agg1
    k_agg256<<<(E + 15) / 16, 256, 0, stream>>>(row, col, norm, h1, agg1, E);
    // + self loop + bias, relu (in place -> agg1 is now layer-1 activation)
    {
        int total = N * H;
        k_final_relu<256><<<(total + 255) / 256, 256, 0, stream>>>(agg1, h1, dinv, b1, total);
    }

    // layer 2: h2 = agg1 @ W2 ; fused epilogue stores d_out = dinv^2*h2 + b2
    k_gemm<true><<<dim3(Fout / BN, (N + BM - 1) / BM), 256, 0, stream>>>(
        agg1, W2, h2, N, Fout, H, dinv, b2, out);
    // edge scatter into d_out (atomic on top of the fused epilogue store)
    k_agg128<<<(E + 15) / 16, 256, 0, stream>>>(row, col, norm, h2, out, E);
}

// Round 2
// 935.718 us; speedup vs baseline: 2.4889x; 2.4889x over previous
//
#include <hip/hip_runtime.h>

// ================= normalization + CSR build =================

__global__ void k_deg_init(float* deg, int* cnt, int n) {
    int i = blockIdx.x * blockDim.x + threadIdx.x;
    if (i < n) { deg[i] = 1.0f; cnt[i] = 0; }   // deg starts at 1.0 (self loop)
}

__global__ void k_deg_count(const int* __restrict__ col, const float* __restrict__ w,
                            float* __restrict__ deg, int* __restrict__ cnt, int E) {
    int i = blockIdx.x * blockDim.x + threadIdx.x;
    if (i < E) {
        int c = col[i];
        atomicAdd(&deg[c], w[i]);
        atomicAdd(&cnt[c], 1);
    }
}

__global__ void k_dinv(float* deg, int n) {
    int i = blockIdx.x * blockDim.x + threadIdx.x;
    if (i < n) {
        float d = deg[i];
        deg[i] = d > 0.0f ? rsqrtf(d) : 0.0f;
    }
}

// --- 3-pass exclusive scan of cnt[N] -> rowptr[N+1], cursor[N] ---
// Pass A: per-block (1024 elems) sums.
__global__ void k_scan_bsum(const int* __restrict__ cnt, int* __restrict__ bsum, int N) {
    __shared__ int sdata[256];
    int base = blockIdx.x * 1024;
    int t = threadIdx.x;
    int s = 0;
    #pragma unroll
    for (int j = 0; j < 4; ++j) { int i = base + t * 4 + j; if (i < N) s += cnt[i]; }
    sdata[t] = s; __syncthreads();
    for (int off = 128; off > 0; off >>= 1) {
        if (t < off) sdata[t] += sdata[t + off];
        __syncthreads();
    }
    if (t == 0) bsum[blockIdx.x] = sdata[0];
}

// Pass B: single block exclusive-scans block sums (nb <= 256), writes total.
__global__ void k_scan_boff(int* __restrict__ bsum, int nb, int* __restrict__ total) {
    __shared__ int buf[256];
    int t = threadIdx.x;
    int v = (t < nb) ? bsum[t] : 0;
    buf[t] = v; __syncthreads();
    for (int off = 1; off < 256; off <<= 1) {
        int x = (t >= off) ? buf[t - off] : 0;
        __syncthreads();
        buf[t] += x;
        __syncthreads();
    }
    if (t < nb) bsum[t] = buf[t] - v;          // exclusive
    if (t == nb - 1) *total = buf[t];          // inclusive total -> rowptr[N]
}

// Pass C: full exclusive positions.
__global__ void k_scan_write(const int* __restrict__ cnt, const int* __restrict__ bsum,
                             int* __restrict__ rowptr, int* __restrict__ cursor, int N) {
    __shared__ int sdata[256];
    int base = blockIdx.x * 1024;
    int t = threadIdx.x;
    int c[4]; int s = 0;
    #pragma unroll
    for (int j = 0; j < 4; ++j) {
        int i = base + t * 4 + j;
        c[j] = (i < N) ? cnt[i] : 0;
        s += c[j];
    }
    sdata[t] = s; __syncthreads();
    for (int off = 1; off < 256; off <<= 1) {
        int x = (t >= off) ? sdata[t - off] : 0;
        __syncthreads();
        sdata[t] += x;
        __syncthreads();
    }
    int excl = sdata[t] - s + bsum[blockIdx.x];
    #pragma unroll
    for (int j = 0; j < 4; ++j) {
        int i = base + t * 4 + j;
        if (i < N) { rowptr[i] = excl; cursor[i] = excl; }
        excl += c[j];
    }
}

// Scatter edges into CSR order; fuse norm computation.
__global__ void k_scatter(const int* __restrict__ row, const int* __restrict__ col,
                          const float* __restrict__ w, const float* __restrict__ dinv,
                          int* __restrict__ cursor, int* __restrict__ rows_s,
                          float* __restrict__ nrm_s, int E) {
    int i = blockIdx.x * blockDim.x + threadIdx.x;
    if (i < E) {
        int r = row[i], c = col[i];
        int p = atomicAdd(&cursor[c], 1);
        rows_s[p] = r;
        nrm_s[p] = dinv[r] * w[i] * dinv[c];
    }
}

// ================= fp32 tiled GEMM: C[M,Nc] = A[M,K] @ B[K,Nc] =================
#define BM 64
#define BN 64
#define BK 16

__global__ void k_gemm(const float* __restrict__ A, const float* __restrict__ B,
                       float* __restrict__ C, int M, int Nc, int K) {
    __shared__ float As[BK][BM + 1];
    __shared__ float Bs[BK][BN];

    const int t  = threadIdx.x;
    const int tx = t & 15;
    const int ty = t >> 4;
    const int bm = blockIdx.y * BM;
    const int bn = blockIdx.x * BN;

    float acc[4][4] = {};

    for (int k0 = 0; k0 < K; k0 += BK) {
        #pragma unroll
        for (int l = 0; l < 4; ++l) {
            int idx = t + l * 256;
            int i  = idx >> 4;
            int kk = idx & 15;
            As[kk][i] = (bm + i < M) ? A[(size_t)(bm + i) * K + k0 + kk] : 0.0f;
        }
        #pragma unroll
        for (int l = 0; l < 4; ++l) {
            int idx = t + l * 256;
            int kk = idx >> 6;
            int j  = idx & 63;
            Bs[kk][j] = B[(size_t)(k0 + kk) * Nc + bn + j];
        }
        __syncthreads();
        #pragma unroll
        for (int kk = 0; kk < BK; ++kk) {
            float a[4], b[4];
            #pragma unroll
            for (int u = 0; u < 4; ++u) a[u] = As[kk][ty * 4 + u];
            #pragma unroll
            for (int v = 0; v < 4; ++v) b[v] = Bs[kk][tx * 4 + v];
            #pragma unroll
            for (int u = 0; u < 4; ++u)
                #pragma unroll
                for (int v = 0; v < 4; ++v) acc[u][v] += a[u] * b[v];
        }
        __syncthreads();
    }

    #pragma unroll
    for (int u = 0; u < 4; ++u) {
        int i = bm + ty * 4 + u;
        if (i < M) {
            #pragma unroll
            for (int v = 0; v < 4; ++v) {
                C[(size_t)i * Nc + bn + tx * 4 + v] = acc[u][v];
            }
        }
    }
}

// ================= CSR aggregation: one block per destination node =================
// out[node,f] = (sum_e nrm[e]*h[rows[e],f]) + dinv[node]^2*h[node,f] + bias[f], opt ReLU.
template <int F, bool RELU>
__global__ void k_aggr(const int* __restrict__ rowptr, const int* __restrict__ rows,
                       const float* __restrict__ nrm, const float* __restrict__ h,
                       const float* __restrict__ dinv, const float* __restrict__ bias,
                       float* __restrict__ out) {
    int node = blockIdx.x;
    int f = threadIdx.x;
    int beg = rowptr[node], end = rowptr[node + 1];

    float acc0 = 0.0f, acc1 = 0.0f;
    int e = beg;
    for (; e + 1 < end; e += 2) {
        int   r0 = rows[e],     r1 = rows[e + 1];
        float n0 = nrm[e],      n1 = nrm[e + 1];
        acc0 += n0 * h[(size_t)r0 * F + f];
        acc1 += n1 * h[(size_t)r1 * F + f];
    }
    if (e < end) acc0 += nrm[e] * h[(size_t)rows[e] * F + f];

    float di = dinv[node];
    float v = acc0 + acc1 + di * di * h[(size_t)node * F + f] + bias[f];
    if (RELU) v = fmaxf(v, 0.0f);
    out[(size_t)node * F + f] = v;
}

// ================= launcher =================

extern "C" void kernel_launch(void* const* d_in, const int* in_sizes, int n_in,
                              void* d_out, int out_size, void* d_ws, size_t ws_size,
                              hipStream_t stream) {
    const float* x  = (const float*)d_in[0];
    const int*   ei = (const int*)d_in[1];
    const float* ew = (const float*)d_in[2];
    const float* W1 = (const float*)d_in[3];
    const float* b1 = (const float*)d_in[4];
    const float* W2 = (const float*)d_in[5];
    const float* b2 = (const float*)d_in[6];
    float* out = (float*)d_out;

    const int E    = in_sizes[2];
    const int H    = in_sizes[4];       // 256
    const int Fout = in_sizes[6];       // 128
    const int Fin  = in_sizes[3] / H;   // 256
    const int N    = in_sizes[0] / Fin; // 50000

    const int* row = ei;
    const int* col = ei + E;

    // workspace layout (all 4-byte elems)
    char* p = (char*)d_ws;
    float* dinv   = (float*)p;  p += (size_t)N * 4;
    int*   rowptr = (int*)p;    p += (size_t)(N + 1) * 4;
    int*   cursor = (int*)p;    p += (size_t)N * 4;
    int*   cnt    = (int*)p;    p += (size_t)N * 4;
    int*   rows_s = (int*)p;    p += (size_t)E * 4;
    float* nrm_s  = (float*)p;  p += (size_t)E * 4;
    float* h1     = (float*)p;  p += (size_t)N * H * 4;
    float* a1     = (float*)p;  p += (size_t)N * H * 4;   // relu'd layer-1 activation
    float* h2     = (float*)p;  p += (size_t)N * Fout * 4;

    const int nb = (N + 1023) / 1024;

    // degree + dinv
    k_deg_init<<<(N + 255) / 256, 256, 0, stream>>>(dinv, cnt, N);
    k_deg_count<<<(E + 255) / 256, 256, 0, stream>>>(col, ew, dinv, cnt, E);
    k_dinv<<<(N + 255) / 256, 256, 0, stream>>>(dinv, N);

    // CSR build (sorted by destination col)
    k_scan_bsum<<<nb, 256, 0, stream>>>(cnt, cursor /*reuse as bsum? no*/, N);
    // NOTE: we need a separate bsum buffer; reuse cnt is unsafe. Use cursor temporarily:
    // cursor is overwritten by k_scan_write afterwards, and pass B only touches [0,nb).
    k_scan_boff<<<1, 256, 0, stream>>>(cursor, nb, rowptr + N);
    k_scan_write<<<nb, 256, 0, stream>>>(cnt, cursor, rowptr, cnt /*cursor out*/, N);
    // cnt now holds cursor values; cursor[0..nb) held block offsets (consumed).
    k_scatter<<<(E + 255) / 256, 256, 0, stream>>>(row, col, ew, dinv, cnt, rows_s, nrm_s, E);

    // layer 1: h1 = x @ W1 ; a1 = relu(aggr(h1) + self + b1)
    k_gemm<<<dim3(H / BN, (N + BM - 1) / BM), 256, 0, stream>>>(x, W1, h1, N, H, Fin);
    k_aggr<256, true><<<N, 256, 0, stream>>>(rowptr, rows_s, nrm_s, h1, dinv, b1, a1);

    // layer 2: h2 = a1 @ W2 ; out = aggr(h2) + self + b2
    k_gemm<<<dim3(Fout / BN, (N + BM - 1) / BM), 256, 0, stream>>>(a1, W2, h2, N, Fout, H);
    k_aggr<128, false><<<N, 128, 0, stream>>>(rowptr, rows_s, nrm_s, h2, dinv, b2, out);
}

// Round 4
// 715.240 us; speedup vs baseline: 3.2561x; 1.3083x over previous
//
#include <hip/hip_runtime.h>

typedef __attribute__((ext_vector_type(8))) short  short8;
typedef __attribute__((ext_vector_type(4))) float  f32x4;
typedef __attribute__((ext_vector_type(4))) ushort us4;
typedef __attribute__((ext_vector_type(4))) uint   u32x4;

__device__ __forceinline__ float bf2f(ushort u) {
    union { uint i; float f; } c; c.i = ((uint)u) << 16; return c.f;
}
__device__ __forceinline__ ushort f2bf(float f) {
    union { float f; uint i; } c; c.f = f;
    uint b = c.i + 0x7fffu + ((c.i >> 16) & 1u);   // RNE, no NaN inputs here
    return (ushort)(b >> 16);
}

// ================= normalization + CSR build =================

__global__ void k_deg_init(float* deg, int* cnt, int n) {
    int i = blockIdx.x * blockDim.x + threadIdx.x;
    if (i < n) { deg[i] = 1.0f; cnt[i] = 0; }   // deg starts at 1.0 (self loop)
}

__global__ void k_deg_count(const int* __restrict__ col, const float* __restrict__ w,
                            float* __restrict__ deg, int* __restrict__ cnt, int E) {
    int i = blockIdx.x * blockDim.x + threadIdx.x;
    if (i < E) {
        int c = col[i];
        atomicAdd(&deg[c], w[i]);
        atomicAdd(&cnt[c], 1);
    }
}

__global__ void k_dinv(float* deg, int n) {
    int i = blockIdx.x * blockDim.x + threadIdx.x;
    if (i < n) {
        float d = deg[i];
        deg[i] = d > 0.0f ? rsqrtf(d) : 0.0f;
    }
}

__global__ void k_scan_bsum(const int* __restrict__ cnt, int* __restrict__ bsum, int N) {
    __shared__ int sdata[256];
    int base = blockIdx.x * 1024;
    int t = threadIdx.x;
    int s = 0;
    #pragma unroll
    for (int j = 0; j < 4; ++j) { int i = base + t * 4 + j; if (i < N) s += cnt[i]; }
    sdata[t] = s; __syncthreads();
    for (int off = 128; off > 0; off >>= 1) {
        if (t < off) sdata[t] += sdata[t + off];
        __syncthreads();
    }
    if (t == 0) bsum[blockIdx.x] = sdata[0];
}

__global__ void k_scan_boff(int* __restrict__ bsum, int nb, int* __restrict__ total) {
    __shared__ int buf[256];
    int t = threadIdx.x;
    int v = (t < nb) ? bsum[t] : 0;
    buf[t] = v; __syncthreads();
    for (int off = 1; off < 256; off <<= 1) {
        int x = (t >= off) ? buf[t - off] : 0;
        __syncthreads();
        buf[t] += x;
        __syncthreads();
    }
    if (t < nb) bsum[t] = buf[t] - v;
    if (t == nb - 1) *total = buf[t];
}

__global__ void k_scan_write(const int* __restrict__ cnt, const int* __restrict__ bsum,
                             int* __restrict__ rowptr, int* __restrict__ cursor, int N) {
    __shared__ int sdata[256];
    int base = blockIdx.x * 1024;
    int t = threadIdx.x;
    int c[4]; int s = 0;
    #pragma unroll
    for (int j = 0; j < 4; ++j) {
        int i = base + t * 4 + j;
        c[j] = (i < N) ? cnt[i] : 0;
        s += c[j];
    }
    sdata[t] = s; __syncthreads();
    for (int off = 1; off < 256; off <<= 1) {
        int x = (t >= off) ? sdata[t - off] : 0;
        __syncthreads();
        sdata[t] += x;
        __syncthreads();
    }
    int excl = sdata[t] - s + bsum[blockIdx.x];
    #pragma unroll
    for (int j = 0; j < 4; ++j) {
        int i = base + t * 4 + j;
        if (i < N) { rowptr[i] = excl; cursor[i] = excl; }
        excl += c[j];
    }
}

__global__ void k_scatter(const int* __restrict__ row, const int* __restrict__ col,
                          const float* __restrict__ w, const float* __restrict__ dinv,
                          int* __restrict__ cursor, int* __restrict__ rows_s,
                          float* __restrict__ nrm_s, int E) {
    int i = blockIdx.x * blockDim.x + threadIdx.x;
    if (i < E) {
        int r = row[i], c = col[i];
        int p = atomicAdd(&cursor[c], 1);
        rows_s[p] = r;
        nrm_s[p] = dinv[r] * w[i] * dinv[c];
    }
}

// ================= weight split + transpose: W[K][N] -> WT{h,l}[N][K] ==========
__global__ void k_splitT(const float* __restrict__ W, ushort* __restrict__ Th,
                         ushort* __restrict__ Tl, int K, int N) {
    int i = blockIdx.x * 256 + threadIdx.x;
    if (i < K * N) {
        int k = i / N, n = i - k * N;
        float v = W[i];
        ushort hi = f2bf(v);
        ushort lo = f2bf(v - bf2f(hi));
        Th[(size_t)n * K + k] = hi;
        Tl[(size_t)n * K + k] = lo;
    }
}

// ================= MFMA GEMM: C_bf16[M,Nc] = A_f32[M,K] @ W[K,Nc] ==============
// A split inline to bf16 hi/lo; W pre-split/transposed as BT{h,l}[Nc][K].
// 3-product: Ah*Bh + Ah*Bl + Al*Bh. Tile 128x64, BK=32, 256 thr (4 waves 2x2).
#define LDA 40   // padded LDS row stride (bf16 elems) to break bank conflicts

__global__ __launch_bounds__(256)
void k_gemm3(const float* __restrict__ A, const ushort* __restrict__ BTh,
             const ushort* __restrict__ BTl, ushort* __restrict__ C,
             int M, int Nc, int K) {
    __shared__ __align__(16) ushort As[2][128][LDA];
    __shared__ __align__(16) ushort Bs[2][64][LDA];

    const int t    = threadIdx.x;
    const int lane = t & 63;
    const int wid  = t >> 6;
    const int wm   = wid >> 1;       // 0..1 (m dir, 64 rows each)
    const int wn   = wid & 1;        // 0..1 (n dir, 32 cols each)
    const int ml   = lane & 15;
    const int kq   = lane >> 4;      // 0..3
    const int bm   = blockIdx.y * 128;
    const int bn   = blockIdx.x * 64;

    f32x4 acc[4][2];
    #pragma unroll
    for (int mt = 0; mt < 4; ++mt)
        #pragma unroll
        for (int nt = 0; nt < 2; ++nt) acc[mt][nt] = (f32x4){0.f, 0.f, 0.f, 0.f};

    for (int k0 = 0; k0 < K; k0 += 32) {
        // ---- stage A (fp32 -> bf16 hi/lo), 128x32 ----
        #pragma unroll
        for (int it = 0; it < 4; ++it) {
            int idx = (t + it * 256) * 4;      // element index in 128*32
            int r  = idx >> 5;
            int kk = idx & 31;
            int grow = bm + r;
            f32x4 v = (f32x4){0.f, 0.f, 0.f, 0.f};
            if (grow < M) v = *(const f32x4*)&A[(size_t)grow * K + k0 + kk];
            us4 hi, lo;
            #pragma unroll
            for (int j = 0; j < 4; ++j) {
                ushort h = f2bf(v[j]);
                hi[j] = h;
                lo[j] = f2bf(v[j] - bf2f(h));
            }
            *(us4*)&As[0][r][kk] = hi;
            *(us4*)&As[1][r][kk] = lo;
        }
        // ---- stage B (pre-split bf16), 64x32 per half ----
        {
            int idx = t * 8;                   // 2048 elems
            int n  = idx >> 5;
            int kk = idx & 31;
            u32x4 vh = *(const u32x4*)&BTh[(size_t)(bn + n) * K + k0 + kk];
            *(u32x4*)&Bs[0][n][kk] = vh;
            u32x4 vl = *(const u32x4*)&BTl[(size_t)(bn + n) * K + k0 + kk];
            *(u32x4*)&Bs[1][n][kk] = vl;
        }
        __syncthreads();

        short8 a[4][2], b[2][2];
        #pragma unroll
        for (int mt = 0; mt < 4; ++mt) {
            a[mt][0] = *(const short8*)&As[0][wm * 64 + mt * 16 + ml][kq * 8];
            a[mt][1] = *(const short8*)&As[1][wm * 64 + mt * 16 + ml][kq * 8];
        }
        #pragma unroll
        for (int nt = 0; nt < 2; ++nt) {
            b[nt][0] = *(const short8*)&Bs[0][wn * 32 + nt * 16 + ml][kq * 8];
            b[nt][1] = *(const short8*)&Bs[1][wn * 32 + nt * 16 + ml][kq * 8];
        }
        #pragma unroll
        for (int mt = 0; mt < 4; ++mt)
            #pragma unroll
            for (int nt = 0; nt < 2; ++nt) {
                acc[mt][nt] = __builtin_amdgcn_mfma_f32_16x16x32_bf16(a[mt][0], b[nt][0], acc[mt][nt], 0, 0, 0);
                acc[mt][nt] = __builtin_amdgcn_mfma_f32_16x16x32_bf16(a[mt][0], b[nt][1], acc[mt][nt], 0, 0, 0);
                acc[mt][nt] = __builtin_amdgcn_mfma_f32_16x16x32_bf16(a[mt][1], b[nt][0], acc[mt][nt], 0, 0, 0);
            }
        __syncthreads();
    }

    // ---- epilogue: C/D layout col=lane&15, row=(lane>>4)*4+reg ----
    #pragma unroll
    for (int mt = 0; mt < 4; ++mt) {
        int rbase = bm + wm * 64 + mt * 16 + kq * 4;
        #pragma unroll
        for (int nt = 0; nt < 2; ++nt) {
            int colg = bn + wn * 32 + nt * 16 + ml;
            #pragma unroll
            for (int r = 0; r < 4; ++r) {
                int rr = rbase + r;
                if (rr < M) C[(size_t)rr * Nc + colg] = f2bf(acc[mt][nt][r]);
            }
        }
    }
}

// ================= CSR aggregation over bf16 h, fp32 out =======================
// out[node,f] = sum_e nrm[e]*h[rows[e],f] + dinv[node]^2*h[node,f] + bias[f]
template <int F, bool RELU>
__global__ __launch_bounds__(256)
void k_aggrv(const int* __restrict__ rowptr, const int* __restrict__ rows,
             const float* __restrict__ nrm, const ushort* __restrict__ h,
             const float* __restrict__ dinv, const float* __restrict__ bias,
             float* __restrict__ out) {
    constexpr int FQ = F / 4;          // feature quads
    constexpr int NSUB = 256 / FQ;     // edges in flight
    __shared__ float red[NSUB][F];

    int node = blockIdx.x;
    int t = threadIdx.x;
    int q = t & (FQ - 1);
    int sub = t / FQ;
    int beg = rowptr[node], end = rowptr[node + 1];

    float a0 = 0.f, a1 = 0.f, a2 = 0.f, a3 = 0.f;
    for (int e = beg + sub; e < end; e += NSUB) {
        int r = rows[e];
        float nv = nrm[e];
        us4 hv = *(const us4*)&h[(size_t)r * F + q * 4];
        a0 += nv * bf2f(hv[0]);
        a1 += nv * bf2f(hv[1]);
        a2 += nv * bf2f(hv[2]);
        a3 += nv * bf2f(hv[3]);
    }
    red[sub][q * 4 + 0] = a0;
    red[sub][q * 4 + 1] = a1;
    red[sub][q * 4 + 2] = a2;
    red[sub][q * 4 + 3] = a3;
    __syncthreads();

    if (t < F) {
        float s = 0.f;
        #pragma unroll
        for (int u = 0; u < NSUB; ++u) s += red[u][t];
        float di = dinv[node];
        float v = s + di * di * bf2f(h[(size_t)node * F + t]) + bias[t];
        if (RELU) v = fmaxf(v, 0.f);
        out[(size_t)node * F + t] = v;
    }
}

// ================= launcher =================

static inline char* bump(char*& p, size_t bytes) {
    char* r = p;
    p += (bytes + 255) & ~(size_t)255;
    return r;
}

extern "C" void kernel_launch(void* const* d_in, const int* in_sizes, int n_in,
                              void* d_out, int out_size, void* d_ws, size_t ws_size,
                              hipStream_t stream) {
    const float* x  = (const float*)d_in[0];
    const int*   ei = (const int*)d_in[1];
    const float* ew = (const float*)d_in[2];
    const float* W1 = (const float*)d_in[3];
    const float* b1 = (const float*)d_in[4];
    const float* W2 = (const float*)d_in[5];
    const float* b2 = (const float*)d_in[6];
    float* out = (float*)d_out;

    const int E    = in_sizes[2];
    const int H    = in_sizes[4];       // 256
    const int Fout = in_sizes[6];       // 128
    const int Fin  = in_sizes[3] / H;   // 256
    const int N    = in_sizes[0] / Fin; // 50000

    const int* row = ei;
    const int* col = ei + E;

    char* p = (char*)d_ws;
    float*  dinv   = (float*)bump(p, (size_t)N * 4);
    int*    rowptr = (int*)bump(p, (size_t)(N + 1) * 4);
    int*    cursor = (int*)bump(p, (size_t)N * 4);
    int*    cnt    = (int*)bump(p, (size_t)N * 4);
    int*    rows_s = (int*)bump(p, (size_t)E * 4);
    float*  nrm_s  = (float*)bump(p, (size_t)E * 4);
    ushort* WT1h   = (ushort*)bump(p, (size_t)Fin * H * 2);
    ushort* WT1l   = (ushort*)bump(p, (size_t)Fin * H * 2);
    ushort* WT2h   = (ushort*)bump(p, (size_t)H * Fout * 2);
    ushort* WT2l   = (ushort*)bump(p, (size_t)H * Fout * 2);
    ushort* h1     = (ushort*)bump(p, (size_t)N * H * 2);     // bf16
    float*  a1     = (float*)bump(p, (size_t)N * H * 4);      // fp32 activation
    ushort* h2     = (ushort*)bump(p, (size_t)N * Fout * 2);  // bf16

    const int nb = (N + 1023) / 1024;

    // degree + dinv
    k_deg_init<<<(N + 255) / 256, 256, 0, stream>>>(dinv, cnt, N);
    k_deg_count<<<(E + 255) / 256, 256, 0, stream>>>(col, ew, dinv, cnt, E);
    k_dinv<<<(N + 255) / 256, 256, 0, stream>>>(dinv, N);

    // weight split+transpose (independent, tiny)
    k_splitT<<<(Fin * H + 255) / 256, 256, 0, stream>>>(W1, WT1h, WT1l, Fin, H);
    k_splitT<<<(H * Fout + 255) / 256, 256, 0, stream>>>(W2, WT2h, WT2l, H, Fout);

    // CSR build (dst-sorted); cursor temporarily holds block sums, cnt becomes cursor
    k_scan_bsum<<<nb, 256, 0, stream>>>(cnt, cursor, N);
    k_scan_boff<<<1, 256, 0, stream>>>(cursor, nb, rowptr + N);
    k_scan_write<<<nb, 256, 0, stream>>>(cnt, cursor, rowptr, cnt, N);
    k_scatter<<<(E + 255) / 256, 256, 0, stream>>>(row, col, ew, dinv, cnt, rows_s, nrm_s, E);

    // layer 1: h1 = bf16(x @ W1); a1 = relu(aggr(h1) + self + b1)  [fp32]
    k_gemm3<<<dim3(H / 64, (N + 127) / 128), 256, 0, stream>>>(x, WT1h, WT1l, h1, N, H, Fin);
    k_aggrv<256, true><<<N, 256, 0, stream>>>(rowptr, rows_s, nrm_s, h1, dinv, b1, a1);

    // layer 2: h2 = bf16(a1 @ W2); out = aggr(h2) + self + b2
    k_gemm3<<<dim3(Fout / 64, (N + 127) / 128), 256, 0, stream>>>(a1, WT2h, WT2l, h2, N, Fout, H);
    k_aggrv<128, false><<<N, 256, 0, stream>>>(rowptr, rows_s, nrm_s, h2, dinv, b2, out);
}

// Round 5
// 682.696 us; speedup vs baseline: 3.4113x; 1.0477x over previous
//
#include <hip/hip_runtime.h>

typedef __attribute__((ext_vector_type(8))) short  short8;
typedef __attribute__((ext_vector_type(4))) float  f32x4;
typedef __attribute__((ext_vector_type(4))) ushort us4;
typedef __attribute__((ext_vector_type(4))) uint   u32x4;

__device__ __forceinline__ float bf2f(ushort u) {
    union { uint i; float f; } c; c.i = ((uint)u) << 16; return c.f;
}
__device__ __forceinline__ ushort f2bf(float f) {
    union { float f; uint i; } c; c.f = f;
    uint b = c.i + 0x7fffu + ((c.i >> 16) & 1u);   // RNE, no NaN inputs here
    return (ushort)(b >> 16);
}

// ================= normalization + CSR build =================

__global__ void k_deg_init(float* deg, int* cnt, int n) {
    int i = blockIdx.x * blockDim.x + threadIdx.x;
    if (i < n) { deg[i] = 1.0f; cnt[i] = 0; }   // deg starts at 1.0 (self loop)
}

__global__ void k_deg_count(const int* __restrict__ col, const float* __restrict__ w,
                            float* __restrict__ deg, int* __restrict__ cnt, int E) {
    int i = blockIdx.x * blockDim.x + threadIdx.x;
    if (i < E) {
        int c = col[i];
        atomicAdd(&deg[c], w[i]);
        atomicAdd(&cnt[c], 1);
    }
}

__global__ void k_dinv(float* deg, int n) {
    int i = blockIdx.x * blockDim.x + threadIdx.x;
    if (i < n) {
        float d = deg[i];
        deg[i] = d > 0.0f ? rsqrtf(d) : 0.0f;
    }
}

__global__ void k_scan_bsum(const int* __restrict__ cnt, int* __restrict__ bsum, int N) {
    __shared__ int sdata[256];
    int base = blockIdx.x * 1024;
    int t = threadIdx.x;
    int s = 0;
    #pragma unroll
    for (int j = 0; j < 4; ++j) { int i = base + t * 4 + j; if (i < N) s += cnt[i]; }
    sdata[t] = s; __syncthreads();
    for (int off = 128; off > 0; off >>= 1) {
        if (t < off) sdata[t] += sdata[t + off];
        __syncthreads();
    }
    if (t == 0) bsum[blockIdx.x] = sdata[0];
}

__global__ void k_scan_boff(int* __restrict__ bsum, int nb, int* __restrict__ total) {
    __shared__ int buf[256];
    int t = threadIdx.x;
    int v = (t < nb) ? bsum[t] : 0;
    buf[t] = v; __syncthreads();
    for (int off = 1; off < 256; off <<= 1) {
        int x = (t >= off) ? buf[t - off] : 0;
        __syncthreads();
        buf[t] += x;
        __syncthreads();
    }
    if (t < nb) bsum[t] = buf[t] - v;
    if (t == nb - 1) *total = buf[t];
}

__global__ void k_scan_write(const int* __restrict__ cnt, const int* __restrict__ bsum,
                             int* __restrict__ rowptr, int* __restrict__ cursor, int N) {
    __shared__ int sdata[256];
    int base = blockIdx.x * 1024;
    int t = threadIdx.x;
    int c[4]; int s = 0;
    #pragma unroll
    for (int j = 0; j < 4; ++j) {
        int i = base + t * 4 + j;
        c[j] = (i < N) ? cnt[i] : 0;
        s += c[j];
    }
    sdata[t] = s; __syncthreads();
    for (int off = 1; off < 256; off <<= 1) {
        int x = (t >= off) ? sdata[t - off] : 0;
        __syncthreads();
        sdata[t] += x;
        __syncthreads();
    }
    int excl = sdata[t] - s + bsum[blockIdx.x];
    #pragma unroll
    for (int j = 0; j < 4; ++j) {
        int i = base + t * 4 + j;
        if (i < N) { rowptr[i] = excl; cursor[i] = excl; }
        excl += c[j];
    }
}

// Scatter edges into dst-sorted CSR as packed records: low16 = src row (N<=65536),
// high16 = bf16(norm).
__global__ void k_scatter(const int* __restrict__ row, const int* __restrict__ col,
                          const float* __restrict__ w, const float* __restrict__ dinv,
                          int* __restrict__ cursor, uint* __restrict__ edges, int E) {
    int i = blockIdx.x * blockDim.x + threadIdx.x;
    if (i < E) {
        int r = row[i], c = col[i];
        int p = atomicAdd(&cursor[c], 1);
        float nv = dinv[r] * w[i] * dinv[c];
        edges[p] = (uint)(ushort)r | ((uint)f2bf(nv) << 16);
    }
}

// ================= weight split + transpose: W[K][N] -> WT{h,l}[N][K] ==========
__global__ void k_splitT(const float* __restrict__ W, ushort* __restrict__ Th,
                         ushort* __restrict__ Tl, int K, int N) {
    int i = blockIdx.x * 256 + threadIdx.x;
    if (i < K * N) {
        int k = i / N, n = i - k * N;
        float v = W[i];
        ushort hi = f2bf(v);
        ushort lo = f2bf(v - bf2f(hi));
        Th[(size_t)n * K + k] = hi;
        Tl[(size_t)n * K + k] = lo;
    }
}

// ================= MFMA GEMM: h_pan[panel][m][32] = bf16(A_f32[M,K] @ W[K,Nc]) ==
// A split inline to bf16 hi/lo; W pre-split/transposed as BT{h,l}[Nc][K].
// 3-product: Ah*Bh + Ah*Bl + Al*Bh. Tile 128x64, BK=32, 256 thr (4 waves 2x2).
// Output written PANEL-MAJOR: feature panels of 32, panel p contiguous over rows.
#define LDA 40   // padded LDS row stride (bf16 elems)

__global__ __launch_bounds__(256)
void k_gemm3(const float* __restrict__ A, const ushort* __restrict__ BTh,
             const ushort* __restrict__ BTl, ushort* __restrict__ Cpan,
             int M, int Nc, int K) {
    __shared__ __align__(16) ushort As[2][128][LDA];
    __shared__ __align__(16) ushort Bs[2][64][LDA];

    const int t    = threadIdx.x;
    const int lane = t & 63;
    const int wid  = t >> 6;
    const int wm   = wid >> 1;
    const int wn   = wid & 1;
    const int ml   = lane & 15;
    const int kq   = lane >> 4;
    const int bm   = blockIdx.y * 128;
    const int bn   = blockIdx.x * 64;

    f32x4 acc[4][2];
    #pragma unroll
    for (int mt = 0; mt < 4; ++mt)
        #pragma unroll
        for (int nt = 0; nt < 2; ++nt) acc[mt][nt] = (f32x4){0.f, 0.f, 0.f, 0.f};

    for (int k0 = 0; k0 < K; k0 += 32) {
        #pragma unroll
        for (int it = 0; it < 4; ++it) {
            int idx = (t + it * 256) * 4;
            int r  = idx >> 5;
            int kk = idx & 31;
            int grow = bm + r;
            f32x4 v = (f32x4){0.f, 0.f, 0.f, 0.f};
            if (grow < M) v = *(const f32x4*)&A[(size_t)grow * K + k0 + kk];
            us4 hi, lo;
            #pragma unroll
            for (int j = 0; j < 4; ++j) {
                ushort h = f2bf(v[j]);
                hi[j] = h;
                lo[j] = f2bf(v[j] - bf2f(h));
            }
            *(us4*)&As[0][r][kk] = hi;
            *(us4*)&As[1][r][kk] = lo;
        }
        {
            int idx = t * 8;
            int n  = idx >> 5;
            int kk = idx & 31;
            u32x4 vh = *(const u32x4*)&BTh[(size_t)(bn + n) * K + k0 + kk];
            *(u32x4*)&Bs[0][n][kk] = vh;
            u32x4 vl = *(const u32x4*)&BTl[(size_t)(bn + n) * K + k0 + kk];
            *(u32x4*)&Bs[1][n][kk] = vl;
        }
        __syncthreads();

        short8 a[4][2], b[2][2];
        #pragma unroll
        for (int mt = 0; mt < 4; ++mt) {
            a[mt][0] = *(const short8*)&As[0][wm * 64 + mt * 16 + ml][kq * 8];
            a[mt][1] = *(const short8*)&As[1][wm * 64 + mt * 16 + ml][kq * 8];
        }
        #pragma unroll
        for (int nt = 0; nt < 2; ++nt) {
            b[nt][0] = *(const short8*)&Bs[0][wn * 32 + nt * 16 + ml][kq * 8];
            b[nt][1] = *(const short8*)&Bs[1][wn * 32 + nt * 16 + ml][kq * 8];
        }
        #pragma unroll
        for (int mt = 0; mt < 4; ++mt)
            #pragma unroll
            for (int nt = 0; nt < 2; ++nt) {
                acc[mt][nt] = __builtin_amdgcn_mfma_f32_16x16x32_bf16(a[mt][0], b[nt][0], acc[mt][nt], 0, 0, 0);
                acc[mt][nt] = __builtin_amdgcn_mfma_f32_16x16x32_bf16(a[mt][0], b[nt][1], acc[mt][nt], 0, 0, 0);
                acc[mt][nt] = __builtin_amdgcn_mfma_f32_16x16x32_bf16(a[mt][1], b[nt][0], acc[mt][nt], 0, 0, 0);
            }
        __syncthreads();
    }

    // epilogue: C/D layout col=lane&15, row=(lane>>4)*4+reg; panel-major store
    #pragma unroll
    for (int mt = 0; mt < 4; ++mt) {
        int rbase = bm + wm * 64 + mt * 16 + kq * 4;
        #pragma unroll
        for (int nt = 0; nt < 2; ++nt) {
            int colg = bn + wn * 32 + nt * 16 + ml;
            size_t pbase = (size_t)(colg >> 5) * M * 32 + (colg & 31);
            #pragma unroll
            for (int r = 0; r < 4; ++r) {
                int rr = rbase + r;
                if (rr < M) Cpan[pbase + (size_t)rr * 32] = f2bf(acc[mt][nt][r]);
            }
        }
    }
}

// ================= panel CSR aggregation ======================================
// h_pan: [npan][N][32] bf16. out: row-major [N][F] fp32.
// Block = 4 waves; wave handles nodes; lanes: sub=lane>>3 (8 edges in flight),
// q=lane&7 (feature quad). panel = blockIdx.x % npan -> XCD-pinned panel reuse.
#define NODES_PER_CHUNK 16

template <bool RELU>
__global__ __launch_bounds__(256)
void k_aggr_pan(const int* __restrict__ rowptr, const uint* __restrict__ edges,
                const ushort* __restrict__ hpan, const float* __restrict__ dinv,
                const float* __restrict__ bias, float* __restrict__ out,
                int F, int npan, int N) {
    const int bid   = blockIdx.x;
    const int p     = bid % npan;
    const int chunk = bid / npan;
    const int wave  = threadIdx.x >> 6;
    const int lane  = threadIdx.x & 63;
    const int sub   = lane >> 3;
    const int q     = lane & 7;

    const ushort* hp = hpan + (size_t)p * N * 32;
    const int fbase = p * 32 + q * 4;
    f32x4 bv = *(const f32x4*)&bias[fbase];

    #pragma unroll
    for (int i = 0; i < NODES_PER_CHUNK / 4; ++i) {
        int node = chunk * NODES_PER_CHUNK + i * 4 + wave;
        if (node >= N) return;
        int beg = rowptr[node], end = rowptr[node + 1];

        f32x4 acc = (f32x4){0.f, 0.f, 0.f, 0.f};
        for (int e = beg + sub; e < end; e += 8) {
            uint pk = edges[e];
            int r = (int)(pk & 0xffffu);
            float nv = bf2f((ushort)(pk >> 16));
            us4 hv = *(const us4*)&hp[(size_t)r * 32 + q * 4];
            acc[0] += nv * bf2f(hv[0]);
            acc[1] += nv * bf2f(hv[1]);
            acc[2] += nv * bf2f(hv[2]);
            acc[3] += nv * bf2f(hv[3]);
        }
        // reduce over sub (lane bits 3,4,5)
        #pragma unroll
        for (int m = 8; m <= 32; m <<= 1) {
            acc[0] += __shfl_xor(acc[0], m, 64);
            acc[1] += __shfl_xor(acc[1], m, 64);
            acc[2] += __shfl_xor(acc[2], m, 64);
            acc[3] += __shfl_xor(acc[3], m, 64);
        }
        if (sub == 0) {
            float di = dinv[node];
            float d2 = di * di;
            us4 hs = *(const us4*)&hp[(size_t)node * 32 + q * 4];
            f32x4 v;
            v[0] = acc[0] + d2 * bf2f(hs[0]) + bv[0];
            v[1] = acc[1] + d2 * bf2f(hs[1]) + bv[1];
            v[2] = acc[2] + d2 * bf2f(hs[2]) + bv[2];
            v[3] = acc[3] + d2 * bf2f(hs[3]) + bv[3];
            if (RELU) {
                v[0] = fmaxf(v[0], 0.f); v[1] = fmaxf(v[1], 0.f);
                v[2] = fmaxf(v[2], 0.f); v[3] = fmaxf(v[3], 0.f);
            }
            *(f32x4*)&out[(size_t)node * F + fbase] = v;
        }
    }
}

// ================= launcher =================

static inline char* bump(char*& p, size_t bytes) {
    char* r = p;
    p += (bytes + 255) & ~(size_t)255;
    return r;
}

extern "C" void kernel_launch(void* const* d_in, const int* in_sizes, int n_in,
                              void* d_out, int out_size, void* d_ws, size_t ws_size,
                              hipStream_t stream) {
    const float* x  = (const float*)d_in[0];
    const int*   ei = (const int*)d_in[1];
    const float* ew = (const float*)d_in[2];
    const float* W1 = (const float*)d_in[3];
    const float* b1 = (const float*)d_in[4];
    const float* W2 = (const float*)d_in[5];
    const float* b2 = (const float*)d_in[6];
    float* out = (float*)d_out;

    const int E    = in_sizes[2];
    const int H    = in_sizes[4];       // 256
    const int Fout = in_sizes[6];       // 128
    const int Fin  = in_sizes[3] / H;   // 256
    const int N    = in_sizes[0] / Fin; // 50000 (fits ushort)

    const int* row = ei;
    const int* col = ei + E;

    char* p = (char*)d_ws;
    float*  dinv   = (float*)bump(p, (size_t)N * 4);
    int*    rowptr = (int*)bump(p, (size_t)(N + 1) * 4);
    int*    cursor = (int*)bump(p, (size_t)N * 4);
    int*    cnt    = (int*)bump(p, (size_t)N * 4);
    uint*   edges  = (uint*)bump(p, (size_t)E * 4);
    ushort* WT1h   = (ushort*)bump(p, (size_t)Fin * H * 2);
    ushort* WT1l   = (ushort*)bump(p, (size_t)Fin * H * 2);
    ushort* WT2h   = (ushort*)bump(p, (size_t)H * Fout * 2);
    ushort* WT2l   = (ushort*)bump(p, (size_t)H * Fout * 2);
    ushort* h1     = (ushort*)bump(p, (size_t)N * H * 2);     // panel-major bf16
    float*  a1     = (float*)bump(p, (size_t)N * H * 4);      // row-major fp32
    ushort* h2     = (ushort*)bump(p, (size_t)N * Fout * 2);  // panel-major bf16

    const int nb = (N + 1023) / 1024;

    // degree + dinv
    k_deg_init<<<(N + 255) / 256, 256, 0, stream>>>(dinv, cnt, N);
    k_deg_count<<<(E + 255) / 256, 256, 0, stream>>>(col, ew, dinv, cnt, E);
    k_dinv<<<(N + 255) / 256, 256, 0, stream>>>(dinv, N);

    // weight split+transpose
    k_splitT<<<(Fin * H + 255) / 256, 256, 0, stream>>>(W1, WT1h, WT1l, Fin, H);
    k_splitT<<<(H * Fout + 255) / 256, 256, 0, stream>>>(W2, WT2h, WT2l, H, Fout);

    // CSR build (dst-sorted); cursor temporarily holds block sums, cnt becomes cursor
    k_scan_bsum<<<nb, 256, 0, stream>>>(cnt, cursor, N);
    k_scan_boff<<<1, 256, 0, stream>>>(cursor, nb, rowptr + N);
    k_scan_write<<<nb, 256, 0, stream>>>(cnt, cursor, rowptr, cnt, N);
    k_scatter<<<(E + 255) / 256, 256, 0, stream>>>(row, col, ew, dinv, cnt, edges, E);

    const int chunks = (N + NODES_PER_CHUNK - 1) / NODES_PER_CHUNK;

    // layer 1: h1 = bf16(x @ W1) [panel-major]; a1 = relu(aggr(h1)+self+b1) [row-major]
    k_gemm3<<<dim3(H / 64, (N + 127) / 128), 256, 0, stream>>>(x, WT1h, WT1l, h1, N, H, Fin);
    k_aggr_pan<true><<<chunks * (H / 32), 256, 0, stream>>>(rowptr, edges, h1, dinv, b1, a1, H, H / 32, N);

    // layer 2: h2 = bf16(a1 @ W2) [panel-major]; out = aggr(h2)+self+b2
    k_gemm3<<<dim3(Fout / 64, (N + 127) / 128), 256, 0, stream>>>(a1, WT2h, WT2l, h2, N, Fout, H);
    k_aggr_pan<false><<<chunks * (Fout / 32), 256, 0, stream>>>(rowptr, edges, h2, dinv, b2, out, Fout, Fout / 32, N);
}